// Round 1
// baseline (846.441 us; speedup 1.0000x reference)
//
#include <hip/hip_runtime.h>
#include <math.h>

namespace {
constexpr int B_ = 4, L_ = 1024, E = 128, D = 256;
constexpr int NPOI = 10000, EPOI = 128, NH = 8, FFD = 256;
constexpr int HD = D / NH;            // 32
constexpr int NTOK = B_ * L_;         // 4096
constexpr float LN_EPS = 1e-5f;
}

// block-wide sum of the 256 per-thread values (all threads must call)
__device__ __forceinline__ float block_sum(float v, float* s_red, int tid) {
    s_red[tid] = v;
    __syncthreads();
    for (int s = 128; s > 0; s >>= 1) {
        if (tid < s) s_red[tid] += s_red[tid + s];
        __syncthreads();
    }
    float r = s_red[0];
    __syncthreads();
    return r;
}

// ---------------- Kernel A: per-token embeddings -> x (NTOK,3,D) ----------------
__global__ __launch_bounds__(256)
void embed_kernel(const float* __restrict__ iq,
                  const float* __restrict__ poi_coors,
                  const float* __restrict__ poi_embed,
                  const float* __restrict__ sp_w1, const float* __restrict__ sp_b1,
                  const float* __restrict__ sp_w2, const float* __restrict__ sp_b2,
                  const float* __restrict__ four_w, const float* __restrict__ four_b,
                  const float* __restrict__ te_w,  const float* __restrict__ te_b,
                  const float* __restrict__ poi_ln_g, const float* __restrict__ poi_ln_b,
                  const float* __restrict__ poi_w, const float* __restrict__ poi_b,
                  const float* __restrict__ tok_emb,
                  const float* __restrict__ tok_ln_g, const float* __restrict__ tok_ln_b,
                  const float* __restrict__ tok_w, const float* __restrict__ tok_b,
                  float* __restrict__ xout)
{
    const int n = blockIdx.x;
    const int tid = threadIdx.x;

    __shared__ float s_red[256];
    __shared__ int   s_redi[256];
    __shared__ float s_t0n[E], s_t1n[E], s_poin[EPOI], s_hsp[E], s_ht[4 * E];
    __shared__ float s_sp[2], s_tt[4];
    __shared__ int   s_tok[2], s_poi;

    if (tid == 0) {
        const float* p = iq + (size_t)n * 8;   // (4,2) per token
        s_sp[0] = p[0];           // iq[n,0,0]
        s_sp[1] = p[2];           // iq[n,1,0]
        float ts = p[4];          // iq[n,2,0]
        float dt = p[6];          // iq[n,3,0]
        s_tok[0] = (int)p[1];     // iq[n,0,1]
        s_tok[1] = (int)p[5];     // iq[n,2,1]
        s_tt[0] = fmodf(ts, 604800.0f) / 86400.0f;
        s_tt[1] = fmodf(ts, 86400.0f) / 3600.0f;
        s_tt[2] = fmodf(ts, 3600.0f) / 60.0f;
        s_tt[3] = dt / 60.0f;
    }
    __syncthreads();

    // ---- POI argmin over NPOI (first-min-index semantics, rn ops = numpy rounding) ----
    {
        const float sx = s_sp[0], sy = s_sp[1];
        float bd = INFINITY; int bi = NPOI;
        for (int i = tid; i < NPOI; i += 256) {
            float dx = __fsub_rn(poi_coors[2 * i], sx);
            float dy = __fsub_rn(poi_coors[2 * i + 1], sy);
            float d  = __fadd_rn(__fmul_rn(dx, dx), __fmul_rn(dy, dy));
            if (d < bd) { bd = d; bi = i; }  // i strictly increasing -> first occurrence
        }
        s_red[tid] = bd; s_redi[tid] = bi;
        __syncthreads();
        for (int s = 128; s > 0; s >>= 1) {
            if (tid < s) {
                float od = s_red[tid + s]; int oi = s_redi[tid + s];
                if (od < s_red[tid] || (od == s_red[tid] && oi < s_redi[tid])) {
                    s_red[tid] = od; s_redi[tid] = oi;
                }
            }
            __syncthreads();
        }
        if (tid == 0) s_poi = s_redi[0];
        __syncthreads();
    }

    // ---- LayerNorm(tok_emb[tok0]), (tok_emb[tok1]), (poi_embed[poi]) : 128-vectors ----
    {
        float v = (tid < E) ? tok_emb[s_tok[0] * E + tid] : 0.0f;
        float mean = block_sum((tid < E) ? v : 0.0f, s_red, tid) / (float)E;
        float d = v - mean;
        float var = block_sum((tid < E) ? d * d : 0.0f, s_red, tid) / (float)E;
        if (tid < E) s_t0n[tid] = d / sqrtf(var + LN_EPS) * tok_ln_g[tid] + tok_ln_b[tid];
    }
    {
        float v = (tid < E) ? tok_emb[s_tok[1] * E + tid] : 0.0f;
        float mean = block_sum((tid < E) ? v : 0.0f, s_red, tid) / (float)E;
        float d = v - mean;
        float var = block_sum((tid < E) ? d * d : 0.0f, s_red, tid) / (float)E;
        if (tid < E) s_t1n[tid] = d / sqrtf(var + LN_EPS) * tok_ln_g[tid] + tok_ln_b[tid];
    }
    {
        float v = (tid < EPOI) ? poi_embed[(size_t)s_poi * EPOI + tid] : 0.0f;
        float mean = block_sum((tid < EPOI) ? v : 0.0f, s_red, tid) / (float)EPOI;
        float d = v - mean;
        float var = block_sum((tid < EPOI) ? d * d : 0.0f, s_red, tid) / (float)EPOI;
        if (tid < EPOI) s_poin[tid] = d / sqrtf(var + LN_EPS) * poi_ln_g[tid] + poi_ln_b[tid];
    }

    // ---- hidden vectors ----
    if (tid < E) {
        float h = s_sp[0] * sp_w1[tid] + s_sp[1] * sp_w1[E + tid] + sp_b1[tid];
        s_hsp[tid] = (h >= 0.0f) ? h : 0.01f * h;
    }
    for (int j = tid; j < 4 * E; j += 256) {
        int f = j >> 7;                       // j = f*E + e, E = 128
        float c = cosf(s_tt[f] * four_w[j] + four_b[j]);
        s_ht[j] = (c >= 0.0f) ? c : 0.01f * c;
    }
    __syncthreads();

    // ---- projections: thread tid owns output column d = tid ----
    float a_t0 = tok_b[tid], a_t1 = a_t0;
    for (int e = 0; e < E; ++e) {
        float w = tok_w[e * D + tid];
        a_t0 += s_t0n[e] * w;
        a_t1 += s_t1n[e] * w;
    }
    float a_sp = sp_b2[tid];
    for (int e = 0; e < E; ++e) a_sp += s_hsp[e] * sp_w2[e * D + tid];
    float a_poi = poi_b[tid];
    for (int e = 0; e < EPOI; ++e) a_poi += s_poin[e] * poi_w[e * D + tid];
    float a_te = te_b[tid];
    for (int j = 0; j < 4 * E; ++j) a_te += s_ht[j] * te_w[j * D + tid];

    float* xr = xout + (size_t)n * 3 * D;
    xr[tid]         = a_sp  + a_t0;   // sp_e
    xr[D + tid]     = a_te  + a_t1;   // t_e
    xr[2 * D + tid] = a_poi + a_t0;   // poi_e
}

// ---------------- Kernel B: MHA(3-seq) + LN + FF + LN + mean + pos-encode ----------------
__global__ __launch_bounds__(256)
void mha_ff_kernel(const float* __restrict__ xin,
                   const float* __restrict__ wqkv, const float* __restrict__ bqkv,
                   const float* __restrict__ wout, const float* __restrict__ bout,
                   const float* __restrict__ ln1g, const float* __restrict__ ln1b,
                   const float* __restrict__ fw1, const float* __restrict__ fb1,
                   const float* __restrict__ fw2, const float* __restrict__ fb2,
                   const float* __restrict__ ln2g, const float* __restrict__ ln2b,
                   const int* __restrict__ positions,
                   float* __restrict__ out)
{
    const int n = blockIdx.x, tid = threadIdx.x;
    __shared__ float xs[3 * D], qm[3 * D], km[3 * D], vm[3 * D], om[3 * D];
    __shared__ float hf[3 * FFD];
    __shared__ float att[NH * 9];
    __shared__ float s_red[256];

    for (int i = tid; i < 3 * D; i += 256) xs[i] = xin[(size_t)n * 3 * D + i];
    __syncthreads();

    // QKV: column tid of each of q,k,v for the 3 rows
    for (int r = 0; r < 3; ++r) {
        float aq = bqkv[tid], ak = bqkv[D + tid], av = bqkv[2 * D + tid];
        const float* xr = xs + r * D;
        for (int e = 0; e < D; ++e) {
            float xv = xr[e];
            const float* w = wqkv + (size_t)e * 3 * D;
            aq += xv * w[tid];
            ak += xv * w[D + tid];
            av += xv * w[2 * D + tid];
        }
        qm[r * D + tid] = aq; km[r * D + tid] = ak; vm[r * D + tid] = av;
    }
    __syncthreads();

    // attention scores s[h][q][k]
    if (tid < NH * 9) {
        int h = tid / 9, rr = (tid % 9) / 3, kk = tid % 3;
        const float* qp = qm + rr * D + h * HD;
        const float* kp = km + kk * D + h * HD;
        float s = 0.0f;
        for (int t = 0; t < HD; ++t) s += qp[t] * kp[t];
        att[tid] = s / sqrtf((float)HD);
    }
    __syncthreads();
    // softmax over k (groups of 3)
    if (tid < NH * 3) {
        float* a = att + tid * 3;
        float m = fmaxf(a[0], fmaxf(a[1], a[2]));
        float e0 = expf(a[0] - m), e1 = expf(a[1] - m), e2 = expf(a[2] - m);
        float inv = 1.0f / (e0 + e1 + e2);
        a[0] = e0 * inv; a[1] = e1 * inv; a[2] = e2 * inv;
    }
    __syncthreads();

    // o = att @ v  (column tid belongs to head tid>>5)
    {
        int h = tid >> 5;
        for (int r = 0; r < 3; ++r) {
            const float* a = att + h * 9 + r * 3;
            om[r * D + tid] = a[0] * vm[tid] + a[1] * vm[D + tid] + a[2] * vm[2 * D + tid];
        }
    }
    __syncthreads();

    // out-proj, residual
    float pr[3];
    for (int r = 0; r < 3; ++r) {
        float a = bout[tid];
        const float* orow = om + r * D;
        for (int e = 0; e < D; ++e) a += orow[e] * wout[(size_t)e * D + tid];
        pr[r] = a;
    }
    __syncthreads();
    for (int r = 0; r < 3; ++r) om[r * D + tid] = xs[r * D + tid] + pr[r];
    __syncthreads();

    // LN1 -> xs
    for (int r = 0; r < 3; ++r) {
        float v = om[r * D + tid];
        float mean = block_sum(v, s_red, tid) / (float)D;
        float d = v - mean;
        float var = block_sum(d * d, s_red, tid) / (float)D;
        xs[r * D + tid] = d / sqrtf(var + LN_EPS) * ln1g[tid] + ln1b[tid];
    }
    __syncthreads();

    // FF: hidden
    for (int r = 0; r < 3; ++r) {
        float a = fb1[tid];
        const float* xr = xs + r * D;
        for (int e = 0; e < D; ++e) a += xr[e] * fw1[(size_t)e * FFD + tid];
        hf[r * FFD + tid] = fmaxf(a, 0.0f);
    }
    __syncthreads();
    // FF: out + residual
    for (int r = 0; r < 3; ++r) {
        float a = fb2[tid];
        const float* hr = hf + r * FFD;
        for (int e = 0; e < FFD; ++e) a += hr[e] * fw2[(size_t)e * D + tid];
        pr[r] = xs[r * D + tid] + a;
    }
    __syncthreads();
    for (int r = 0; r < 3; ++r) om[r * D + tid] = pr[r];
    __syncthreads();

    // LN2 + modality mean + positional encodings
    float m3 = 0.0f;
    for (int r = 0; r < 3; ++r) {
        float v = om[r * D + tid];
        float mean = block_sum(v, s_red, tid) / (float)D;
        float d = v - mean;
        float var = block_sum(d * d, s_red, tid) / (float)D;
        m3 += d / sqrtf(var + LN_EPS) * ln2g[tid] + ln2b[tid];
    }
    m3 /= 3.0f;

    int p0 = positions[(size_t)n * 2];
    int p1 = positions[(size_t)n * 2 + 1];
    int fi = tid >> 1;
    float freq = expf(-logf(10000.0f) * (2.0f * fi) / (float)D);
    float a0 = (float)p0 * freq, a1 = (float)p1 * freq;
    float pe = (tid & 1) ? (cosf(a0) + cosf(a1)) : (sinf(a0) + sinf(a1));
    out[(size_t)n * D + tid] = m3 + pe;
}

extern "C" void kernel_launch(void* const* d_in, const int* in_sizes, int n_in,
                              void* d_out, int out_size, void* d_ws, size_t ws_size,
                              hipStream_t stream)
{
    const float* iq        = (const float*)d_in[0];
    const int*   positions = (const int*)d_in[1];
    const float* poi_coors = (const float*)d_in[2];
    const float* poi_embed = (const float*)d_in[3];
    const float* sp_w1     = (const float*)d_in[4];
    const float* sp_b1     = (const float*)d_in[5];
    const float* sp_w2     = (const float*)d_in[6];
    const float* sp_b2     = (const float*)d_in[7];
    const float* four_w    = (const float*)d_in[8];
    const float* four_b    = (const float*)d_in[9];
    const float* te_w      = (const float*)d_in[10];
    const float* te_b      = (const float*)d_in[11];
    const float* poi_ln_g  = (const float*)d_in[12];
    const float* poi_ln_b  = (const float*)d_in[13];
    const float* poi_w     = (const float*)d_in[14];
    const float* poi_b     = (const float*)d_in[15];
    const float* tok_emb   = (const float*)d_in[16];
    const float* tok_ln_g  = (const float*)d_in[17];
    const float* tok_ln_b  = (const float*)d_in[18];
    const float* tok_w     = (const float*)d_in[19];
    const float* tok_b     = (const float*)d_in[20];
    const float* mha_in_w  = (const float*)d_in[21];
    const float* mha_in_b  = (const float*)d_in[22];
    const float* mha_out_w = (const float*)d_in[23];
    const float* mha_out_b = (const float*)d_in[24];
    const float* ln1_g     = (const float*)d_in[25];
    const float* ln1_b     = (const float*)d_in[26];
    const float* ff_w1     = (const float*)d_in[27];
    const float* ff_b1     = (const float*)d_in[28];
    const float* ff_w2     = (const float*)d_in[29];
    const float* ff_b2     = (const float*)d_in[30];
    const float* ln2_g     = (const float*)d_in[31];
    const float* ln2_b     = (const float*)d_in[32];

    float* xws = (float*)d_ws;   // (NTOK, 3, D) fp32 = 12.6 MB

    embed_kernel<<<NTOK, 256, 0, stream>>>(
        iq, poi_coors, poi_embed, sp_w1, sp_b1, sp_w2, sp_b2, four_w, four_b,
        te_w, te_b, poi_ln_g, poi_ln_b, poi_w, poi_b, tok_emb, tok_ln_g,
        tok_ln_b, tok_w, tok_b, xws);

    mha_ff_kernel<<<NTOK, 256, 0, stream>>>(
        xws, mha_in_w, mha_in_b, mha_out_w, mha_out_b, ln1_g, ln1_b,
        ff_w1, ff_b1, ff_w2, ff_b2, ln2_g, ln2_b, positions, (float*)d_out);
}

// Round 2
// 514.151 us; speedup vs baseline: 1.6463x; 1.6463x over previous
//
#include <hip/hip_runtime.h>
#include <math.h>

namespace {
constexpr int E = 128, D = 256;
constexpr int NPOI = 10000, NH = 8, FFD = 256;
constexpr int HD = D / NH;            // 32
constexpr int NTOK = 4096;            // B*L
constexpr int TA = 8;                 // tokens/block, embed kernel
constexpr int TB = 4;                 // tokens/block, transformer kernel (12 rows)
constexpr float LN_EPS = 1e-5f;
}

// 64-lane wave sum
__device__ __forceinline__ float wsum64(float v) {
#pragma unroll
    for (int m = 1; m < 64; m <<= 1) v += __shfl_xor(v, m);
    return v;
}

// sum each of 12 per-thread values across all 256 threads (2 barriers)
__device__ __forceinline__ void block_sum12(float v[12], float* s_p, int tid) {
    const int lane = tid & 63, w = tid >> 6;
#pragma unroll
    for (int r = 0; r < 12; ++r) {
        float x = wsum64(v[r]);
        if (lane == 0) s_p[r * 4 + w] = x;
    }
    __syncthreads();
#pragma unroll
    for (int r = 0; r < 12; ++r)
        v[r] = s_p[r * 4 + 0] + s_p[r * 4 + 1] + s_p[r * 4 + 2] + s_p[r * 4 + 3];
    __syncthreads();
}

// LayerNorm of a 128-vector done by one 64-lane wave (no block barriers)
__device__ __forceinline__ void ln128_wave(const float* __restrict__ src,
                                           const float* __restrict__ g,
                                           const float* __restrict__ b,
                                           float* __restrict__ dst, int lane) {
    float v0 = src[lane], v1 = src[64 + lane];
    float mean = wsum64(v0 + v1) * (1.0f / 128.0f);
    float d0 = v0 - mean, d1 = v1 - mean;
    float var = wsum64(d0 * d0 + d1 * d1) * (1.0f / 128.0f);
    float inv = sqrtf(var + LN_EPS);
    dst[lane]      = d0 / inv * g[lane]      + b[lane];
    dst[64 + lane] = d1 / inv * g[64 + lane] + b[64 + lane];
}

// ---------------- Kernel A: per-token embeddings -> x (NTOK,3,D), TA tokens/block ----
__global__ __launch_bounds__(256)
void embed_kernel(const float* __restrict__ iq,
                  const float* __restrict__ poi_coors,
                  const float* __restrict__ poi_embed,
                  const float* __restrict__ sp_w1, const float* __restrict__ sp_b1,
                  const float* __restrict__ sp_w2, const float* __restrict__ sp_b2,
                  const float* __restrict__ four_w, const float* __restrict__ four_b,
                  const float* __restrict__ te_w,  const float* __restrict__ te_b,
                  const float* __restrict__ poi_ln_g, const float* __restrict__ poi_ln_b,
                  const float* __restrict__ poi_w, const float* __restrict__ poi_b,
                  const float* __restrict__ tok_emb,
                  const float* __restrict__ tok_ln_g, const float* __restrict__ tok_ln_b,
                  const float* __restrict__ tok_w, const float* __restrict__ tok_b,
                  float* __restrict__ xout)
{
    const int n0 = blockIdx.x * TA;
    const int tid = threadIdx.x;

    // hidden layout per token: [0:128 t0n][128:256 t1n][256:384 poin][384:512 hsp][512:1024 ht]
    __shared__ float s_hid[TA * 1024];            // 32 KB
    __shared__ float s_red[TA * 256];             // 8 KB  (argmin dist)
    __shared__ int   s_redi[TA * 256];            // 8 KB  (argmin idx)
    __shared__ float s_sp[TA][2], s_tt[TA][4];
    __shared__ int   s_tok[TA][2], s_poi[TA];

    if (tid < TA) {
        const float* p = iq + (size_t)(n0 + tid) * 8;   // (4,2) per token
        s_sp[tid][0] = p[0];
        s_sp[tid][1] = p[2];
        float ts = p[4];
        float dt = p[6];
        s_tok[tid][0] = (int)p[1];
        s_tok[tid][1] = (int)p[5];
        s_tt[tid][0] = fmodf(ts, 604800.0f) / 86400.0f;
        s_tt[tid][1] = fmodf(ts, 86400.0f) / 3600.0f;
        s_tt[tid][2] = fmodf(ts, 3600.0f) / 60.0f;
        s_tt[tid][3] = dt / 60.0f;
    }
    __syncthreads();

    // ---- POI argmin for all TA tokens in one scan ----
    {
        float sx[TA], sy[TA], bd[TA];
        int bi[TA];
#pragma unroll
        for (int t = 0; t < TA; ++t) { sx[t] = s_sp[t][0]; sy[t] = s_sp[t][1]; bd[t] = INFINITY; bi[t] = NPOI; }
        const float2* pc = (const float2*)poi_coors;
        for (int i = tid; i < NPOI; i += 256) {
            float2 p = pc[i];
#pragma unroll
            for (int t = 0; t < TA; ++t) {
                float dx = __fsub_rn(p.x, sx[t]);
                float dy = __fsub_rn(p.y, sy[t]);
                float d  = __fadd_rn(__fmul_rn(dx, dx), __fmul_rn(dy, dy));
                if (d < bd[t]) { bd[t] = d; bi[t] = i; }  // ascending i -> first occurrence
            }
        }
#pragma unroll
        for (int t = 0; t < TA; ++t) { s_red[t * 256 + tid] = bd[t]; s_redi[t * 256 + tid] = bi[t]; }
        __syncthreads();
        for (int s = 128; s > 0; s >>= 1) {
            if (tid < s) {
#pragma unroll
                for (int t = 0; t < TA; ++t) {
                    float* rd = s_red + t * 256; int* ri = s_redi + t * 256;
                    float od = rd[tid + s]; int oi = ri[tid + s];
                    if (od < rd[tid] || (od == rd[tid] && oi < ri[tid])) { rd[tid] = od; ri[tid] = oi; }
                }
            }
            __syncthreads();
        }
        if (tid < TA) s_poi[tid] = s_redi[tid * 256];
        __syncthreads();
    }

    // ---- per-wave: LayerNorms (3 x 128) + hsp for 2 tokens each; all threads: ht ----
    {
        const int w = tid >> 6, lane = tid & 63;
#pragma unroll
        for (int k = 0; k < 2; ++k) {
            const int t = w * 2 + k;
            float* hb = s_hid + t * 1024;
            ln128_wave(tok_emb + (size_t)s_tok[t][0] * E, tok_ln_g, tok_ln_b, hb, lane);
            ln128_wave(tok_emb + (size_t)s_tok[t][1] * E, tok_ln_g, tok_ln_b, hb + 128, lane);
            ln128_wave(poi_embed + (size_t)s_poi[t] * E, poi_ln_g, poi_ln_b, hb + 256, lane);
#pragma unroll
            for (int l = lane; l < 128; l += 64) {
                float h = s_sp[t][0] * sp_w1[l] + s_sp[t][1] * sp_w1[128 + l] + sp_b1[l];
                hb[384 + l] = (h >= 0.0f) ? h : 0.01f * h;
            }
        }
        for (int j = tid; j < TA * 512; j += 256) {
            int t = j >> 9, jj = j & 511, f = jj >> 7;
            float c = cosf(s_tt[t][f] * four_w[jj] + four_b[jj]);
            s_hid[t * 1024 + 512 + jj] = (c >= 0.0f) ? c : 0.01f * c;
        }
    }
    __syncthreads();

    // ---- projections: thread tid owns output column tid ----
    float at0[TA], at1[TA], acc[TA];
    {
        float bb = tok_b[tid];
#pragma unroll
        for (int t = 0; t < TA; ++t) { at0[t] = bb; at1[t] = bb; }
    }
    for (int e = 0; e < 128; e += 4) {
        const float* wp = tok_w + (size_t)e * D + tid;
        float w0 = wp[0], w1 = wp[D], w2 = wp[2 * D], w3 = wp[3 * D];
#pragma unroll
        for (int t = 0; t < TA; ++t) {
            float4 h0 = *(const float4*)(s_hid + t * 1024 + e);
            float4 h1 = *(const float4*)(s_hid + t * 1024 + 128 + e);
            at0[t] += h0.x * w0 + h0.y * w1 + h0.z * w2 + h0.w * w3;
            at1[t] += h1.x * w0 + h1.y * w1 + h1.z * w2 + h1.w * w3;
        }
    }
    // sp_e -> row 0
    {
        float bb = sp_b2[tid];
#pragma unroll
        for (int t = 0; t < TA; ++t) acc[t] = bb;
        for (int e = 0; e < 128; e += 4) {
            const float* wp = sp_w2 + (size_t)e * D + tid;
            float w0 = wp[0], w1 = wp[D], w2 = wp[2 * D], w3 = wp[3 * D];
#pragma unroll
            for (int t = 0; t < TA; ++t) {
                float4 h = *(const float4*)(s_hid + t * 1024 + 384 + e);
                acc[t] += h.x * w0 + h.y * w1 + h.z * w2 + h.w * w3;
            }
        }
#pragma unroll
        for (int t = 0; t < TA; ++t)
            xout[(size_t)(n0 + t) * 3 * D + tid] = acc[t] + at0[t];
    }
    // t_e -> row 1
    {
        float bb = te_b[tid];
#pragma unroll
        for (int t = 0; t < TA; ++t) acc[t] = bb;
        for (int j = 0; j < 512; j += 4) {
            const float* wp = te_w + (size_t)j * D + tid;
            float w0 = wp[0], w1 = wp[D], w2 = wp[2 * D], w3 = wp[3 * D];
#pragma unroll
            for (int t = 0; t < TA; ++t) {
                float4 h = *(const float4*)(s_hid + t * 1024 + 512 + j);
                acc[t] += h.x * w0 + h.y * w1 + h.z * w2 + h.w * w3;
            }
        }
#pragma unroll
        for (int t = 0; t < TA; ++t)
            xout[(size_t)(n0 + t) * 3 * D + D + tid] = acc[t] + at1[t];
    }
    // poi_e -> row 2
    {
        float bb = poi_b[tid];
#pragma unroll
        for (int t = 0; t < TA; ++t) acc[t] = bb;
        for (int e = 0; e < 128; e += 4) {
            const float* wp = poi_w + (size_t)e * D + tid;
            float w0 = wp[0], w1 = wp[D], w2 = wp[2 * D], w3 = wp[3 * D];
#pragma unroll
            for (int t = 0; t < TA; ++t) {
                float4 h = *(const float4*)(s_hid + t * 1024 + 256 + e);
                acc[t] += h.x * w0 + h.y * w1 + h.z * w2 + h.w * w3;
            }
        }
#pragma unroll
        for (int t = 0; t < TA; ++t)
            xout[(size_t)(n0 + t) * 3 * D + 2 * D + tid] = acc[t] + at0[t];
    }
}

// ---------------- Kernel B: MHA + LN + FF + LN + mean + pos-encode, TB tokens/block ----
__global__ __launch_bounds__(256)
void mha_ff_kernel(const float* __restrict__ xin,
                   const float* __restrict__ wqkv, const float* __restrict__ bqkv,
                   const float* __restrict__ wout, const float* __restrict__ bout,
                   const float* __restrict__ ln1g, const float* __restrict__ ln1b,
                   const float* __restrict__ fw1, const float* __restrict__ fb1,
                   const float* __restrict__ fw2, const float* __restrict__ fb2,
                   const float* __restrict__ ln2g, const float* __restrict__ ln2b,
                   const int* __restrict__ positions,
                   float* __restrict__ out)
{
    const int n0 = blockIdx.x * TB;          // 12 rows = TB tokens x 3 modalities
    const int tid = threadIdx.x;

    __shared__ float s_x[12 * D];            // 12 KB: x, later o
    __shared__ float s_qkv[12 * 3 * D];      // 36 KB: qkv, later [xs1 | ffhid]
    __shared__ float s_att[TB * NH * 9];     // 288 floats; also sum12 scratch (48)

    const size_t base = (size_t)n0 * 3 * D;
    for (int i = tid; i < 12 * D; i += 256) s_x[i] = xin[base + i];
    __syncthreads();

    float xres[12];
#pragma unroll
    for (int r = 0; r < 12; ++r) xres[r] = s_x[r * D + tid];

    // ---- QKV ----
    {
        float aq[12], ak[12], av[12];
        float bq = bqkv[tid], bk = bqkv[D + tid], bv = bqkv[2 * D + tid];
#pragma unroll
        for (int r = 0; r < 12; ++r) { aq[r] = bq; ak[r] = bk; av[r] = bv; }
        for (int e = 0; e < D; e += 4) {
            const float* wp = wqkv + (size_t)e * 3 * D;
            float wq0 = wp[tid],            wk0 = wp[D + tid],            wv0 = wp[2 * D + tid];
            float wq1 = wp[3 * D + tid],    wk1 = wp[4 * D + tid],        wv1 = wp[5 * D + tid];
            float wq2 = wp[6 * D + tid],    wk2 = wp[7 * D + tid],        wv2 = wp[8 * D + tid];
            float wq3 = wp[9 * D + tid],    wk3 = wp[10 * D + tid],       wv3 = wp[11 * D + tid];
#pragma unroll
            for (int r = 0; r < 12; ++r) {
                float4 x4 = *(const float4*)(s_x + r * D + e);
                aq[r] += x4.x * wq0 + x4.y * wq1 + x4.z * wq2 + x4.w * wq3;
                ak[r] += x4.x * wk0 + x4.y * wk1 + x4.z * wk2 + x4.w * wk3;
                av[r] += x4.x * wv0 + x4.y * wv1 + x4.z * wv2 + x4.w * wv3;
            }
        }
#pragma unroll
        for (int r = 0; r < 12; ++r) {
            s_qkv[r * 3 * D + tid]         = aq[r];
            s_qkv[r * 3 * D + D + tid]     = ak[r];
            s_qkv[r * 3 * D + 2 * D + tid] = av[r];
        }
    }
    __syncthreads();

    // ---- attention scores: 288 dot-32 ----
    for (int idx = tid; idx < TB * NH * 9; idx += 256) {
        int tok = idx / 72, rem = idx % 72;
        int h = rem / 9, qr = (rem % 9) / 3, kr = rem % 3;
        const float4* q4 = (const float4*)(s_qkv + (tok * 3 + qr) * 3 * D + h * HD);
        const float4* k4 = (const float4*)(s_qkv + (tok * 3 + kr) * 3 * D + D + h * HD);
        float s = 0.0f;
#pragma unroll
        for (int u = 0; u < 8; ++u) {
            float4 a = q4[u], b = k4[u];
            s += a.x * b.x + a.y * b.y + a.z * b.z + a.w * b.w;
        }
        s_att[idx] = s / sqrtf((float)HD);
    }
    __syncthreads();

    // ---- softmax over k (groups of 3) ----
    if (tid < TB * NH * 3) {
        float* a = s_att + tid * 3;
        float m = fmaxf(a[0], fmaxf(a[1], a[2]));
        float e0 = expf(a[0] - m), e1 = expf(a[1] - m), e2 = expf(a[2] - m);
        float inv = 1.0f / (e0 + e1 + e2);
        a[0] = e0 * inv; a[1] = e1 * inv; a[2] = e2 * inv;
    }
    __syncthreads();

    // ---- o = att @ v, write into s_x (residual already in regs) ----
    {
        const int h = tid >> 5;
#pragma unroll
        for (int tok = 0; tok < TB; ++tok) {
            float v0 = s_qkv[(tok * 3 + 0) * 3 * D + 2 * D + tid];
            float v1 = s_qkv[(tok * 3 + 1) * 3 * D + 2 * D + tid];
            float v2 = s_qkv[(tok * 3 + 2) * 3 * D + 2 * D + tid];
#pragma unroll
            for (int qr = 0; qr < 3; ++qr) {
                const float* a = s_att + (tok * 24 + h * 3 + qr) * 3;
                s_x[(tok * 3 + qr) * D + tid] = a[0] * v0 + a[1] * v1 + a[2] * v2;
            }
        }
    }
    __syncthreads();

    // ---- out projection + residual ----
    float val[12];
    {
        float bo = bout[tid];
#pragma unroll
        for (int r = 0; r < 12; ++r) val[r] = bo;
        for (int e = 0; e < D; e += 4) {
            const float* wp = wout + (size_t)e * D + tid;
            float w0 = wp[0], w1 = wp[D], w2 = wp[2 * D], w3 = wp[3 * D];
#pragma unroll
            for (int r = 0; r < 12; ++r) {
                float4 o4 = *(const float4*)(s_x + r * D + e);
                val[r] += o4.x * w0 + o4.y * w1 + o4.z * w2 + o4.w * w3;
            }
        }
#pragma unroll
        for (int r = 0; r < 12; ++r) val[r] += xres[r];
    }

    // ---- LN1 -> y (regs) and s_qkv[0:12*D] ----
    float y[12];
    {
        float s[12];
#pragma unroll
        for (int r = 0; r < 12; ++r) s[r] = val[r];
        block_sum12(s, s_att, tid);
        float d[12];
#pragma unroll
        for (int r = 0; r < 12; ++r) d[r] = val[r] - s[r] * (1.0f / 256.0f);
        float s2[12];
#pragma unroll
        for (int r = 0; r < 12; ++r) s2[r] = d[r] * d[r];
        block_sum12(s2, s_att, tid);
        float g = ln1g[tid], b = ln1b[tid];
#pragma unroll
        for (int r = 0; r < 12; ++r) {
            y[r] = d[r] / sqrtf(s2[r] * (1.0f / 256.0f) + LN_EPS) * g + b;
            s_qkv[r * D + tid] = y[r];
        }
    }
    __syncthreads();

    // ---- FF1: hid = relu(xs1 @ fw1 + b1) -> s_qkv[12*D : 24*D] ----
    {
        float ah[12];
        float b1v = fb1[tid];
#pragma unroll
        for (int r = 0; r < 12; ++r) ah[r] = b1v;
        for (int e = 0; e < D; e += 4) {
            const float* wp = fw1 + (size_t)e * FFD + tid;
            float w0 = wp[0], w1 = wp[FFD], w2 = wp[2 * FFD], w3 = wp[3 * FFD];
#pragma unroll
            for (int r = 0; r < 12; ++r) {
                float4 x4 = *(const float4*)(s_qkv + r * D + e);
                ah[r] += x4.x * w0 + x4.y * w1 + x4.z * w2 + x4.w * w3;
            }
        }
#pragma unroll
        for (int r = 0; r < 12; ++r) s_qkv[12 * D + r * FFD + tid] = fmaxf(ah[r], 0.0f);
    }
    __syncthreads();

    // ---- FF2 + residual + LN2 + modality mean + pos-encode ----
    {
        float af[12];
        float b2v = fb2[tid];
#pragma unroll
        for (int r = 0; r < 12; ++r) af[r] = b2v;
        for (int e = 0; e < FFD; e += 4) {
            const float* wp = fw2 + (size_t)e * D + tid;
            float w0 = wp[0], w1 = wp[D], w2 = wp[2 * D], w3 = wp[3 * D];
#pragma unroll
            for (int r = 0; r < 12; ++r) {
                float4 h4 = *(const float4*)(s_qkv + 12 * D + r * FFD + e);
                af[r] += h4.x * w0 + h4.y * w1 + h4.z * w2 + h4.w * w3;
            }
        }
#pragma unroll
        for (int r = 0; r < 12; ++r) af[r] += y[r];

        float s[12];
#pragma unroll
        for (int r = 0; r < 12; ++r) s[r] = af[r];
        block_sum12(s, s_att, tid);
        float d[12];
#pragma unroll
        for (int r = 0; r < 12; ++r) d[r] = af[r] - s[r] * (1.0f / 256.0f);
        float s2[12];
#pragma unroll
        for (int r = 0; r < 12; ++r) s2[r] = d[r] * d[r];
        block_sum12(s2, s_att, tid);
        float g = ln2g[tid], b = ln2b[tid];
        float z[12];
#pragma unroll
        for (int r = 0; r < 12; ++r)
            z[r] = d[r] / sqrtf(s2[r] * (1.0f / 256.0f) + LN_EPS) * g + b;

        const int fi = tid >> 1;
        const float freq = expf(-logf(10000.0f) * (2.0f * fi) / (float)D);
#pragma unroll
        for (int t = 0; t < TB; ++t) {
            int n = n0 + t;
            float p0 = (float)positions[2 * n], p1 = (float)positions[2 * n + 1];
            float a0 = p0 * freq, a1 = p1 * freq;
            float pe = (tid & 1) ? (cosf(a0) + cosf(a1)) : (sinf(a0) + sinf(a1));
            float m3 = (z[t * 3] + z[t * 3 + 1] + z[t * 3 + 2]) / 3.0f;
            out[(size_t)n * D + tid] = m3 + pe;
        }
    }
}

extern "C" void kernel_launch(void* const* d_in, const int* in_sizes, int n_in,
                              void* d_out, int out_size, void* d_ws, size_t ws_size,
                              hipStream_t stream)
{
    const float* iq        = (const float*)d_in[0];
    const int*   positions = (const int*)d_in[1];
    const float* poi_coors = (const float*)d_in[2];
    const float* poi_embed = (const float*)d_in[3];
    const float* sp_w1     = (const float*)d_in[4];
    const float* sp_b1     = (const float*)d_in[5];
    const float* sp_w2     = (const float*)d_in[6];
    const float* sp_b2     = (const float*)d_in[7];
    const float* four_w    = (const float*)d_in[8];
    const float* four_b    = (const float*)d_in[9];
    const float* te_w      = (const float*)d_in[10];
    const float* te_b      = (const float*)d_in[11];
    const float* poi_ln_g  = (const float*)d_in[12];
    const float* poi_ln_b  = (const float*)d_in[13];
    const float* poi_w     = (const float*)d_in[14];
    const float* poi_b     = (const float*)d_in[15];
    const float* tok_emb   = (const float*)d_in[16];
    const float* tok_ln_g  = (const float*)d_in[17];
    const float* tok_ln_b  = (const float*)d_in[18];
    const float* tok_w     = (const float*)d_in[19];
    const float* tok_b     = (const float*)d_in[20];
    const float* mha_in_w  = (const float*)d_in[21];
    const float* mha_in_b  = (const float*)d_in[22];
    const float* mha_out_w = (const float*)d_in[23];
    const float* mha_out_b = (const float*)d_in[24];
    const float* ln1_g     = (const float*)d_in[25];
    const float* ln1_b     = (const float*)d_in[26];
    const float* ff_w1     = (const float*)d_in[27];
    const float* ff_b1     = (const float*)d_in[28];
    const float* ff_w2     = (const float*)d_in[29];
    const float* ff_b2     = (const float*)d_in[30];
    const float* ln2_g     = (const float*)d_in[31];
    const float* ln2_b     = (const float*)d_in[32];

    float* xws = (float*)d_ws;   // (NTOK, 3, D) fp32 = 12.6 MB

    embed_kernel<<<NTOK / TA, 256, 0, stream>>>(
        iq, poi_coors, poi_embed, sp_w1, sp_b1, sp_w2, sp_b2, four_w, four_b,
        te_w, te_b, poi_ln_g, poi_ln_b, poi_w, poi_b, tok_emb, tok_ln_g,
        tok_ln_b, tok_w, tok_b, xws);

    mha_ff_kernel<<<NTOK / TB, 256, 0, stream>>>(
        xws, mha_in_w, mha_in_b, mha_out_w, mha_out_b, ln1_g, ln1_b,
        ff_w1, ff_b1, ff_w2, ff_b2, ln2_g, ln2_b, positions, (float*)d_out);
}

// Round 4
// 271.075 us; speedup vs baseline: 3.1225x; 1.8967x over previous
//
#include <hip/hip_runtime.h>
#include <math.h>

namespace {
constexpr int E = 128, D = 256;
constexpr int NPOI = 10000, NH = 8, FFD = 256;
constexpr int HD = D / NH;            // 32
constexpr int NTOK = 4096;            // B*L
constexpr int TA = 8;                 // tokens/block, embed kernel
constexpr int TB = 16;                // tokens/block, transformer kernel (48 rows)
constexpr float LN_EPS = 1e-5f;

// packed bf16 weight layout offsets (ushort elements)
constexpr int PK_QKV = 0;             // 48 n-tiles x 8 k-tiles x 512
constexpr int PK_OUT = 196608;        // 16 x 8 x 512
constexpr int PK_FF1 = 262144;
constexpr int PK_FF2 = 327680;
constexpr int PK_TOTAL = 393216;
}

using frag8 = __attribute__((ext_vector_type(8))) short;   // 8 bf16 (4 VGPRs)
using f32x4 = __attribute__((ext_vector_type(4))) float;   // 4 fp32 acc

__device__ __forceinline__ float bf2f(short s) {
    union { unsigned u; float f; } x; x.u = ((unsigned)(unsigned short)s) << 16; return x.f;
}
__device__ __forceinline__ unsigned short f2bf(float f) {
    union { float f; unsigned u; } x; x.f = f;
    unsigned r = x.u + 0x7fffu + ((x.u >> 16) & 1u);
    return (unsigned short)(r >> 16);
}

// 64-lane wave sum
__device__ __forceinline__ float wsum64(float v) {
#pragma unroll
    for (int m = 1; m < 64; m <<= 1) v += __shfl_xor(v, m);
    return v;
}

// LayerNorm of a 128-vector done by one 64-lane wave (no block barriers)
__device__ __forceinline__ void ln128_wave(const float* __restrict__ src,
                                           const float* __restrict__ g,
                                           const float* __restrict__ b,
                                           float* __restrict__ dst, int lane) {
    float v0 = src[lane], v1 = src[64 + lane];
    float mean = wsum64(v0 + v1) * (1.0f / 128.0f);
    float d0 = v0 - mean, d1 = v1 - mean;
    float var = wsum64(d0 * d0 + d1 * d1) * (1.0f / 128.0f);
    float inv = sqrtf(var + LN_EPS);
    dst[lane]      = d0 / inv * g[lane]      + b[lane];
    dst[64 + lane] = d1 / inv * g[64 + lane] + b[64 + lane];
}

// ---------------- Weight prepack: fp32 -> bf16 MFMA-B-fragment order ----------------
// For matrix W (K x N): tile (nt,kt) holds lane l, elem j = W[kt*32+(l>>4)*8+j][nt*16+(l&15)]
// stored at ((nt*8 + kt)*64 + l)*8 + j  (so one frag = one 16B coalesced load)
__global__ __launch_bounds__(256)
void pack_weights(const float* __restrict__ wqkv, const float* __restrict__ wout,
                  const float* __restrict__ fw1,  const float* __restrict__ fw2,
                  unsigned short* __restrict__ pk)
{
    int idx = blockIdx.x * 256 + threadIdx.x;
    if (idx >= PK_TOTAL) return;
    const float* src; int N; int base;
    if (idx < PK_OUT)       { src = wqkv; N = 768; base = PK_QKV; }
    else if (idx < PK_FF1)  { src = wout; N = 256; base = PK_OUT; }
    else if (idx < PK_FF2)  { src = fw1;  N = 256; base = PK_FF1; }
    else                    { src = fw2;  N = 256; base = PK_FF2; }
    int loc = idx - base;
    int j = loc & 7, l = (loc >> 3) & 63, t = loc >> 9;
    int kt = t & 7, nt = t >> 3;
    int k = kt * 32 + (l >> 4) * 8 + j;
    int n = nt * 16 + (l & 15);
    pk[idx] = f2bf(src[(size_t)k * N + n]);
}

// ---------------- Kernel A: per-token embeddings -> x (NTOK,3,D), TA tokens/block ----
__global__ __launch_bounds__(256)
void embed_kernel(const float* __restrict__ iq,
                  const float* __restrict__ poi_coors,
                  const float* __restrict__ poi_embed,
                  const float* __restrict__ sp_w1, const float* __restrict__ sp_b1,
                  const float* __restrict__ sp_w2, const float* __restrict__ sp_b2,
                  const float* __restrict__ four_w, const float* __restrict__ four_b,
                  const float* __restrict__ te_w,  const float* __restrict__ te_b,
                  const float* __restrict__ poi_ln_g, const float* __restrict__ poi_ln_b,
                  const float* __restrict__ poi_w, const float* __restrict__ poi_b,
                  const float* __restrict__ tok_emb,
                  const float* __restrict__ tok_ln_g, const float* __restrict__ tok_ln_b,
                  const float* __restrict__ tok_w, const float* __restrict__ tok_b,
                  float* __restrict__ xout)
{
    const int n0 = blockIdx.x * TA;
    const int tid = threadIdx.x;

    __shared__ float s_hid[TA * 1024];
    __shared__ float s_red[TA * 256];
    __shared__ int   s_redi[TA * 256];
    __shared__ float s_sp[TA][2], s_tt[TA][4];
    __shared__ int   s_tok[TA][2], s_poi[TA];

    if (tid < TA) {
        const float* p = iq + (size_t)(n0 + tid) * 8;
        s_sp[tid][0] = p[0];
        s_sp[tid][1] = p[2];
        float ts = p[4];
        float dt = p[6];
        s_tok[tid][0] = (int)p[1];
        s_tok[tid][1] = (int)p[5];
        s_tt[tid][0] = fmodf(ts, 604800.0f) / 86400.0f;
        s_tt[tid][1] = fmodf(ts, 86400.0f) / 3600.0f;
        s_tt[tid][2] = fmodf(ts, 3600.0f) / 60.0f;
        s_tt[tid][3] = dt / 60.0f;
    }
    __syncthreads();

    {
        float sx[TA], sy[TA], bd[TA];
        int bi[TA];
#pragma unroll
        for (int t = 0; t < TA; ++t) { sx[t] = s_sp[t][0]; sy[t] = s_sp[t][1]; bd[t] = INFINITY; bi[t] = NPOI; }
        const float2* pc = (const float2*)poi_coors;
        for (int i = tid; i < NPOI; i += 256) {
            float2 p = pc[i];
#pragma unroll
            for (int t = 0; t < TA; ++t) {
                float dx = __fsub_rn(p.x, sx[t]);
                float dy = __fsub_rn(p.y, sy[t]);
                float d  = __fadd_rn(__fmul_rn(dx, dx), __fmul_rn(dy, dy));
                if (d < bd[t]) { bd[t] = d; bi[t] = i; }
            }
        }
#pragma unroll
        for (int t = 0; t < TA; ++t) { s_red[t * 256 + tid] = bd[t]; s_redi[t * 256 + tid] = bi[t]; }
        __syncthreads();
        for (int s = 128; s > 0; s >>= 1) {
            if (tid < s) {
#pragma unroll
                for (int t = 0; t < TA; ++t) {
                    float* rd = s_red + t * 256; int* ri = s_redi + t * 256;
                    float od = rd[tid + s]; int oi = ri[tid + s];
                    if (od < rd[tid] || (od == rd[tid] && oi < ri[tid])) { rd[tid] = od; ri[tid] = oi; }
                }
            }
            __syncthreads();
        }
        if (tid < TA) s_poi[tid] = s_redi[tid * 256];
        __syncthreads();
    }

    {
        const int w = tid >> 6, lane = tid & 63;
#pragma unroll
        for (int k = 0; k < 2; ++k) {
            const int t = w * 2 + k;
            float* hb = s_hid + t * 1024;
            ln128_wave(tok_emb + (size_t)s_tok[t][0] * E, tok_ln_g, tok_ln_b, hb, lane);
            ln128_wave(tok_emb + (size_t)s_tok[t][1] * E, tok_ln_g, tok_ln_b, hb + 128, lane);
            ln128_wave(poi_embed + (size_t)s_poi[t] * E, poi_ln_g, poi_ln_b, hb + 256, lane);
#pragma unroll
            for (int l = lane; l < 128; l += 64) {
                float h = s_sp[t][0] * sp_w1[l] + s_sp[t][1] * sp_w1[128 + l] + sp_b1[l];
                hb[384 + l] = (h >= 0.0f) ? h : 0.01f * h;
            }
        }
        for (int j = tid; j < TA * 512; j += 256) {
            int t = j >> 9, jj = j & 511, f = jj >> 7;
            float c = cosf(s_tt[t][f] * four_w[jj] + four_b[jj]);
            s_hid[t * 1024 + 512 + jj] = (c >= 0.0f) ? c : 0.01f * c;
        }
    }
    __syncthreads();

    float at0[TA], at1[TA], acc[TA];
    {
        float bb = tok_b[tid];
#pragma unroll
        for (int t = 0; t < TA; ++t) { at0[t] = bb; at1[t] = bb; }
    }
    for (int e = 0; e < 128; e += 4) {
        const float* wp = tok_w + (size_t)e * D + tid;
        float w0 = wp[0], w1 = wp[D], w2 = wp[2 * D], w3 = wp[3 * D];
#pragma unroll
        for (int t = 0; t < TA; ++t) {
            float4 h0 = *(const float4*)(s_hid + t * 1024 + e);
            float4 h1 = *(const float4*)(s_hid + t * 1024 + 128 + e);
            at0[t] += h0.x * w0 + h0.y * w1 + h0.z * w2 + h0.w * w3;
            at1[t] += h1.x * w0 + h1.y * w1 + h1.z * w2 + h1.w * w3;
        }
    }
    {
        float bb = sp_b2[tid];
#pragma unroll
        for (int t = 0; t < TA; ++t) acc[t] = bb;
        for (int e = 0; e < 128; e += 4) {
            const float* wp = sp_w2 + (size_t)e * D + tid;
            float w0 = wp[0], w1 = wp[D], w2 = wp[2 * D], w3 = wp[3 * D];
#pragma unroll
            for (int t = 0; t < TA; ++t) {
                float4 h = *(const float4*)(s_hid + t * 1024 + 384 + e);
                acc[t] += h.x * w0 + h.y * w1 + h.z * w2 + h.w * w3;
            }
        }
#pragma unroll
        for (int t = 0; t < TA; ++t)
            xout[(size_t)(n0 + t) * 3 * D + tid] = acc[t] + at0[t];
    }
    {
        float bb = te_b[tid];
#pragma unroll
        for (int t = 0; t < TA; ++t) acc[t] = bb;
        for (int j = 0; j < 512; j += 4) {
            const float* wp = te_w + (size_t)j * D + tid;
            float w0 = wp[0], w1 = wp[D], w2 = wp[2 * D], w3 = wp[3 * D];
#pragma unroll
            for (int t = 0; t < TA; ++t) {
                float4 h = *(const float4*)(s_hid + t * 1024 + 512 + j);
                acc[t] += h.x * w0 + h.y * w1 + h.z * w2 + h.w * w3;
            }
        }
#pragma unroll
        for (int t = 0; t < TA; ++t)
            xout[(size_t)(n0 + t) * 3 * D + D + tid] = acc[t] + at1[t];
    }
    {
        float bb = poi_b[tid];
#pragma unroll
        for (int t = 0; t < TA; ++t) acc[t] = bb;
        for (int e = 0; e < 128; e += 4) {
            const float* wp = poi_w + (size_t)e * D + tid;
            float w0 = wp[0], w1 = wp[D], w2 = wp[2 * D], w3 = wp[3 * D];
#pragma unroll
            for (int t = 0; t < TA; ++t) {
                float4 h = *(const float4*)(s_hid + t * 1024 + 256 + e);
                acc[t] += h.x * w0 + h.y * w1 + h.z * w2 + h.w * w3;
            }
        }
#pragma unroll
        for (int t = 0; t < TA; ++t)
            xout[(size_t)(n0 + t) * 3 * D + 2 * D + tid] = acc[t] + at0[t];
    }
}

// ---------------- Kernel B (MFMA): 16 tokens/block = 48 rows, 1 block/CU ----------------
__global__ __launch_bounds__(256)
void mha_ff_mfma(const float* __restrict__ xin,
                 const unsigned short* __restrict__ pk,
                 const float* __restrict__ bqkv, const float* __restrict__ bout,
                 const float* __restrict__ ln1g, const float* __restrict__ ln1b,
                 const float* __restrict__ fb1,  const float* __restrict__ fb2,
                 const float* __restrict__ ln2g, const float* __restrict__ ln2b,
                 const int* __restrict__ positions,
                 float* __restrict__ out)
{
    constexpr int PA = 264;   // bf16 pitch, A-operand region (16B aligned rows)
    constexpr int PQ = 776;   // bf16 pitch, qkv region
    constexpr int PF = 260;   // fp32 pitch, LN scratch
    const int tid = threadIdx.x;
    const int w = tid >> 6, lane = tid & 63;
    const int quad = lane >> 4, l16 = lane & 15;
    const int n0tok = blockIdx.x * TB;
    const float* xg = xin + (size_t)n0tok * 3 * D;

    __shared__ __align__(16) short s_a[48 * PA];     // 25344 B: x -> o -> y_b (A operands)
    __shared__ __align__(16) char  s_u[75264];       // qkv(74496) | later: s_f(49920)+s_h(25344)
    __shared__ float s_att[TB * NH * 9];             // 1152 scores

    short* s_qkv = (short*)s_u;
    float* s_f   = (float*)s_u;
    short* s_h   = (short*)(s_u + 48 * PF * 4);

    // ---- load x (fp32 global) -> s_a bf16 ----
    for (int i = tid * 4; i < 48 * 256; i += 1024) {
        float4 v = *(const float4*)(xg + i);
        int row = i >> 8, col = i & 255;
        ushort4 bb;
        bb.x = f2bf(v.x); bb.y = f2bf(v.y); bb.z = f2bf(v.z); bb.w = f2bf(v.w);
        *(ushort4*)(&s_a[row * PA + col]) = bb;
    }
    __syncthreads();

    // ---- GEMM1: qkv = x @ Wqkv + bias  (M=48, N=768, K=256); wave w: cols [192w,192w+192) ----
    {
        f32x4 acc[36];
#pragma unroll
        for (int nt = 0; nt < 12; ++nt) {
            float bv = bqkv[w * 192 + nt * 16 + l16];
#pragma unroll
            for (int m = 0; m < 3; ++m) { acc[nt * 3 + m][0] = bv; acc[nt * 3 + m][1] = bv; acc[nt * 3 + m][2] = bv; acc[nt * 3 + m][3] = bv; }
        }
        for (int kt = 0; kt < 8; ++kt) {
            frag8 a[3];
#pragma unroll
            for (int m = 0; m < 3; ++m)
                a[m] = *(const frag8*)(&s_a[(m * 16 + l16) * PA + kt * 32 + quad * 8]);
            const unsigned short* bp = pk + PK_QKV + ((size_t)(w * 12) * 8 + kt) * 512 + lane * 8;
#pragma unroll
            for (int nt = 0; nt < 12; ++nt) {
                frag8 b = *(const frag8*)(bp + (size_t)nt * 8 * 512);
#pragma unroll
                for (int m = 0; m < 3; ++m)
                    acc[nt * 3 + m] = __builtin_amdgcn_mfma_f32_16x16x32_bf16(a[m], b, acc[nt * 3 + m], 0, 0, 0);
            }
        }
#pragma unroll
        for (int nt = 0; nt < 12; ++nt)
#pragma unroll
            for (int m = 0; m < 3; ++m)
#pragma unroll
                for (int r = 0; r < 4; ++r) {
                    int row = m * 16 + quad * 4 + r, col = w * 192 + nt * 16 + l16;
                    s_qkv[row * PQ + col] = (short)f2bf(acc[nt * 3 + m][r]);
                }
    }
    __syncthreads();

    // ---- attention scores (fp32 VALU): idx = tok*72 + h*9 + qr*3 + kr ----
    for (int idx = tid; idx < TB * NH * 9; idx += 256) {
        int tok = idx / 72, rem = idx % 72;
        int h = rem / 9, qr = (rem % 9) / 3, kr = rem % 3;
        const short* qp = s_qkv + (tok * 3 + qr) * PQ + h * HD;
        const short* kp = s_qkv + (tok * 3 + kr) * PQ + D + h * HD;
        float s = 0.0f;
#pragma unroll
        for (int u = 0; u < HD; ++u) s += bf2f(qp[u]) * bf2f(kp[u]);
        s_att[idx] = s / sqrtf((float)HD);
    }
    __syncthreads();
    // softmax over k: one triple per index, covering ALL TB*NH*3 = 384 triples
    for (int idx3 = tid; idx3 < TB * NH * 3; idx3 += 256) {
        float* a = s_att + idx3 * 3;
        float m = fmaxf(a[0], fmaxf(a[1], a[2]));
        float e0 = expf(a[0] - m), e1 = expf(a[1] - m), e2 = expf(a[2] - m);
        float inv = 1.0f / (e0 + e1 + e2);
        a[0] = e0 * inv; a[1] = e1 * inv; a[2] = e2 * inv;
    }
    __syncthreads();

    // ---- o = att @ v -> s_a bf16 (x is dead; residual re-read from global) ----
    {
        const int h = tid >> 5;
#pragma unroll
        for (int tok = 0; tok < TB; ++tok) {
            float v0 = bf2f(s_qkv[(tok * 3 + 0) * PQ + 2 * D + tid]);
            float v1 = bf2f(s_qkv[(tok * 3 + 1) * PQ + 2 * D + tid]);
            float v2 = bf2f(s_qkv[(tok * 3 + 2) * PQ + 2 * D + tid]);
#pragma unroll
            for (int qr = 0; qr < 3; ++qr) {
                const float* a = s_att + tok * 72 + h * 9 + qr * 3;
                s_a[(tok * 3 + qr) * PA + tid] = (short)f2bf(a[0] * v0 + a[1] * v1 + a[2] * v2);
            }
        }
    }
    __syncthreads();

    // ---- GEMM2: proj = o @ Wout + bias + x  -> s_f fp32 (qkv dead) ----
    {
        f32x4 acc[12];
#pragma unroll
        for (int nt = 0; nt < 4; ++nt) {
            float bv = bout[w * 64 + nt * 16 + l16];
#pragma unroll
            for (int m = 0; m < 3; ++m) { acc[nt * 3 + m][0] = bv; acc[nt * 3 + m][1] = bv; acc[nt * 3 + m][2] = bv; acc[nt * 3 + m][3] = bv; }
        }
        for (int kt = 0; kt < 8; ++kt) {
            frag8 a[3];
#pragma unroll
            for (int m = 0; m < 3; ++m)
                a[m] = *(const frag8*)(&s_a[(m * 16 + l16) * PA + kt * 32 + quad * 8]);
#pragma unroll
            for (int nt = 0; nt < 4; ++nt) {
                frag8 b = *(const frag8*)(pk + PK_OUT + ((size_t)(w * 4 + nt) * 8 + kt) * 512 + lane * 8);
#pragma unroll
                for (int m = 0; m < 3; ++m)
                    acc[nt * 3 + m] = __builtin_amdgcn_mfma_f32_16x16x32_bf16(a[m], b, acc[nt * 3 + m], 0, 0, 0);
            }
        }
        __syncthreads();   // all A-reads of o and v-region reads done before s_f writes
#pragma unroll
        for (int nt = 0; nt < 4; ++nt)
#pragma unroll
            for (int m = 0; m < 3; ++m)
#pragma unroll
                for (int r = 0; r < 4; ++r) {
                    int row = m * 16 + quad * 4 + r, col = w * 64 + nt * 16 + l16;
                    s_f[row * PF + col] = acc[nt * 3 + m][r] + xg[row * 256 + col];
                }
    }
    __syncthreads();

    // ---- LN1: per-row (wave handles rows w, w+4, ...): y fp32 in-place, y_b bf16 -> s_a ----
#pragma unroll
    for (int rr = 0; rr < 12; ++rr) {
        int row = w + rr * 4, col = lane * 4;
        float4 v = *(const float4*)(&s_f[row * PF + col]);
        float mean = wsum64(v.x + v.y + v.z + v.w) * (1.0f / 256.0f);
        float dx = v.x - mean, dy = v.y - mean, dz = v.z - mean, dw = v.w - mean;
        float var = wsum64(dx * dx + dy * dy + dz * dz + dw * dw) * (1.0f / 256.0f);
        float s = sqrtf(var + LN_EPS);
        float4 g = *(const float4*)(ln1g + col), b = *(const float4*)(ln1b + col);
        float y0 = dx / s * g.x + b.x, y1 = dy / s * g.y + b.y;
        float y2 = dz / s * g.z + b.z, y3 = dw / s * g.w + b.w;
        float4 yv; yv.x = y0; yv.y = y1; yv.z = y2; yv.w = y3;
        *(float4*)(&s_f[row * PF + col]) = yv;
        ushort4 bb; bb.x = f2bf(y0); bb.y = f2bf(y1); bb.z = f2bf(y2); bb.w = f2bf(y3);
        *(ushort4*)(&s_a[row * PA + col]) = bb;
    }
    __syncthreads();

    // ---- FF1: h = relu(y @ FW1 + b1) -> s_h bf16 ----
    {
        f32x4 acc[12];
#pragma unroll
        for (int nt = 0; nt < 4; ++nt) {
            float bv = fb1[w * 64 + nt * 16 + l16];
#pragma unroll
            for (int m = 0; m < 3; ++m) { acc[nt * 3 + m][0] = bv; acc[nt * 3 + m][1] = bv; acc[nt * 3 + m][2] = bv; acc[nt * 3 + m][3] = bv; }
        }
        for (int kt = 0; kt < 8; ++kt) {
            frag8 a[3];
#pragma unroll
            for (int m = 0; m < 3; ++m)
                a[m] = *(const frag8*)(&s_a[(m * 16 + l16) * PA + kt * 32 + quad * 8]);
#pragma unroll
            for (int nt = 0; nt < 4; ++nt) {
                frag8 b = *(const frag8*)(pk + PK_FF1 + ((size_t)(w * 4 + nt) * 8 + kt) * 512 + lane * 8);
#pragma unroll
                for (int m = 0; m < 3; ++m)
                    acc[nt * 3 + m] = __builtin_amdgcn_mfma_f32_16x16x32_bf16(a[m], b, acc[nt * 3 + m], 0, 0, 0);
            }
        }
#pragma unroll
        for (int nt = 0; nt < 4; ++nt)
#pragma unroll
            for (int m = 0; m < 3; ++m)
#pragma unroll
                for (int r = 0; r < 4; ++r) {
                    int row = m * 16 + quad * 4 + r, col = w * 64 + nt * 16 + l16;
                    s_h[row * PA + col] = (short)f2bf(fmaxf(acc[nt * 3 + m][r], 0.0f));
                }
    }
    __syncthreads();

    // ---- FF2: val = h @ FW2 + b2 + y -> s_f (in-place over y) ----
    {
        f32x4 acc[12];
#pragma unroll
        for (int nt = 0; nt < 4; ++nt) {
            float bv = fb2[w * 64 + nt * 16 + l16];
#pragma unroll
            for (int m = 0; m < 3; ++m) { acc[nt * 3 + m][0] = bv; acc[nt * 3 + m][1] = bv; acc[nt * 3 + m][2] = bv; acc[nt * 3 + m][3] = bv; }
        }
        for (int kt = 0; kt < 8; ++kt) {
            frag8 a[3];
#pragma unroll
            for (int m = 0; m < 3; ++m)
                a[m] = *(const frag8*)(&s_h[(m * 16 + l16) * PA + kt * 32 + quad * 8]);
#pragma unroll
            for (int nt = 0; nt < 4; ++nt) {
                frag8 b = *(const frag8*)(pk + PK_FF2 + ((size_t)(w * 4 + nt) * 8 + kt) * 512 + lane * 8);
#pragma unroll
                for (int m = 0; m < 3; ++m)
                    acc[nt * 3 + m] = __builtin_amdgcn_mfma_f32_16x16x32_bf16(a[m], b, acc[nt * 3 + m], 0, 0, 0);
            }
        }
#pragma unroll
        for (int nt = 0; nt < 4; ++nt)
#pragma unroll
            for (int m = 0; m < 3; ++m)
#pragma unroll
                for (int r = 0; r < 4; ++r) {
                    int row = m * 16 + quad * 4 + r, col = w * 64 + nt * 16 + l16;
                    float y = s_f[row * PF + col];               // same lane reads then writes
                    s_f[row * PF + col] = acc[nt * 3 + m][r] + y;
                }
    }
    __syncthreads();

    // ---- LN2 (in-place z) ----
#pragma unroll
    for (int rr = 0; rr < 12; ++rr) {
        int row = w + rr * 4, col = lane * 4;
        float4 v = *(const float4*)(&s_f[row * PF + col]);
        float mean = wsum64(v.x + v.y + v.z + v.w) * (1.0f / 256.0f);
        float dx = v.x - mean, dy = v.y - mean, dz = v.z - mean, dw = v.w - mean;
        float var = wsum64(dx * dx + dy * dy + dz * dz + dw * dw) * (1.0f / 256.0f);
        float s = sqrtf(var + LN_EPS);
        float4 g = *(const float4*)(ln2g + col), b = *(const float4*)(ln2b + col);
        float4 zv;
        zv.x = dx / s * g.x + b.x; zv.y = dy / s * g.y + b.y;
        zv.z = dz / s * g.z + b.z; zv.w = dw / s * g.w + b.w;
        *(float4*)(&s_f[row * PF + col]) = zv;
    }
    __syncthreads();

    // ---- modality mean + positional encodings ----
    {
        const int fi = tid >> 1;
        const float freq = expf(-logf(10000.0f) * (2.0f * fi) / (float)D);
#pragma unroll
        for (int t = 0; t < TB; ++t) {
            int n = n0tok + t;
            float m3 = (s_f[(3 * t) * PF + tid] + s_f[(3 * t + 1) * PF + tid] +
                        s_f[(3 * t + 2) * PF + tid]) / 3.0f;
            float p0 = (float)positions[2 * n], p1 = (float)positions[2 * n + 1];
            float a0 = p0 * freq, a1 = p1 * freq;
            float pe = (tid & 1) ? (cosf(a0) + cosf(a1)) : (sinf(a0) + sinf(a1));
            out[(size_t)n * D + tid] = m3 + pe;
        }
    }
}

extern "C" void kernel_launch(void* const* d_in, const int* in_sizes, int n_in,
                              void* d_out, int out_size, void* d_ws, size_t ws_size,
                              hipStream_t stream)
{
    const float* iq        = (const float*)d_in[0];
    const int*   positions = (const int*)d_in[1];
    const float* poi_coors = (const float*)d_in[2];
    const float* poi_embed = (const float*)d_in[3];
    const float* sp_w1     = (const float*)d_in[4];
    const float* sp_b1     = (const float*)d_in[5];
    const float* sp_w2     = (const float*)d_in[6];
    const float* sp_b2     = (const float*)d_in[7];
    const float* four_w    = (const float*)d_in[8];
    const float* four_b    = (const float*)d_in[9];
    const float* te_w      = (const float*)d_in[10];
    const float* te_b      = (const float*)d_in[11];
    const float* poi_ln_g  = (const float*)d_in[12];
    const float* poi_ln_b  = (const float*)d_in[13];
    const float* poi_w     = (const float*)d_in[14];
    const float* poi_b     = (const float*)d_in[15];
    const float* tok_emb   = (const float*)d_in[16];
    const float* tok_ln_g  = (const float*)d_in[17];
    const float* tok_ln_b  = (const float*)d_in[18];
    const float* tok_w     = (const float*)d_in[19];
    const float* tok_b     = (const float*)d_in[20];
    const float* mha_in_w  = (const float*)d_in[21];
    const float* mha_in_b  = (const float*)d_in[22];
    const float* mha_out_w = (const float*)d_in[23];
    const float* mha_out_b = (const float*)d_in[24];
    const float* ln1_g     = (const float*)d_in[25];
    const float* ln1_b     = (const float*)d_in[26];
    const float* ff_w1     = (const float*)d_in[27];
    const float* ff_b1     = (const float*)d_in[28];
    const float* ff_w2     = (const float*)d_in[29];
    const float* ff_b2     = (const float*)d_in[30];
    const float* ln2_g     = (const float*)d_in[31];
    const float* ln2_b     = (const float*)d_in[32];

    float* xws = (float*)d_ws;                               // (NTOK,3,D) fp32 = 12.58 MB
    unsigned short* pkw = (unsigned short*)((char*)d_ws + (size_t)NTOK * 3 * D * 4);  // 786 KB

    pack_weights<<<(PK_TOTAL + 255) / 256, 256, 0, stream>>>(
        mha_in_w, mha_out_w, ff_w1, ff_w2, pkw);

    embed_kernel<<<NTOK / TA, 256, 0, stream>>>(
        iq, poi_coors, poi_embed, sp_w1, sp_b1, sp_w2, sp_b2, four_w, four_b,
        te_w, te_b, poi_ln_g, poi_ln_b, poi_w, poi_b, tok_emb, tok_ln_g,
        tok_ln_b, tok_w, tok_b, xws);

    mha_ff_mfma<<<NTOK / TB, 256, 0, stream>>>(
        xws, pkw, mha_in_b, mha_out_b, ln1_g, ln1_b,
        ff_b1, ff_b2, ln2_g, ln2_b, positions, (float*)d_out);
}